// Round 1
// baseline (505.393 us; speedup 1.0000x reference)
//
#include <hip/hip_runtime.h>

// AdditiveAttention on MI355X (gfx950)
// B=64, S=2048, D=512, U=512. All inputs fp32; output fp32 (B,D).
//
// R4: scores_k restructured as a 2-phase pipeline (guide T3-minimum):
// K split into 4 chunks of 128; A-stage double-buffered in LDS (2x16KB);
// next chunk's global loads issued BEFORE the current chunk's MFMAs
// (T14 issue-early / write-late) so HBM traffic overlaps compute.
// ctx_k grid 512->1024 blocks (128-row s-chunks) for more loads in flight.

typedef __attribute__((ext_vector_type(8))) short bf16x8;
typedef __attribute__((ext_vector_type(4))) float f32x4;

#if __has_builtin(__builtin_amdgcn_exp2f)
__device__ __forceinline__ float fast_exp2(float x) { return __builtin_amdgcn_exp2f(x); }
#else
__device__ __forceinline__ float fast_exp2(float x) { return exp2f(x); }
#endif
#if __has_builtin(__builtin_amdgcn_rcpf)
__device__ __forceinline__ float fast_rcp(float x) { return __builtin_amdgcn_rcpf(x); }
#else
__device__ __forceinline__ float fast_rcp(float x) { return 1.0f / x; }
#endif

__device__ __forceinline__ unsigned short f2bf(float f) {
  unsigned int u = __float_as_uint(f);
  u += 0x7fffu + ((u >> 16) & 1u);
  return (unsigned short)(u >> 16);
}

// ---------------- k1: Q = query @ W1  (64x2 blocks x 256 thr) ---------------
__global__ void qk(const float* __restrict__ query, const float* __restrict__ W1,
                   float* __restrict__ Q) {
  __shared__ float qrow[512];
  const int b = blockIdx.x, half = blockIdx.y, t = threadIdx.x;
  qrow[t] = query[b * 512 + t];
  qrow[t + 256] = query[b * 512 + t + 256];
  __syncthreads();
  const int u = half * 256 + t;
  float acc = 0.f;
#pragma unroll 8
  for (int k = 0; k < 512; ++k) acc += qrow[k] * W1[(size_t)k * 512 + u];
  Q[b * 512 + u] = acc;
}

// ---------------- k2: Wtf = fragment-ordered bf16(W2^T); also zero out ------
// Wtf[((ntile*16+ks)*64 + quad*16 + l15)*8 + j] = bf16(W2[ks*32+quad*8+j][ntile*16+l15])
__global__ void wt_k(const float* __restrict__ W2, unsigned short* __restrict__ Wtf,
                     float* __restrict__ out0) {
  const int gid = blockIdx.x * 256 + threadIdx.x;  // 0..32767
  out0[gid] = 0.f;                                 // zero d_out for ctx atomics
  const int lane = gid & 63;
  const int g = gid >> 6;  // ntile*16 + ks
  const int ks = g & 15, ntile = g >> 4;
  const int l15 = lane & 15, quad = lane >> 4;
  const int n = ntile * 16 + l15;
  const int k0 = ks * 32 + quad * 8;
  unsigned int p[4];
#pragma unroll
  for (int jj = 0; jj < 4; ++jj) {
    const float a = W2[(size_t)(k0 + 2 * jj) * 512 + n];
    const float b = W2[(size_t)(k0 + 2 * jj + 1) * 512 + n];
    p[jj] = (unsigned int)f2bf(a) | ((unsigned int)f2bf(b) << 16);
  }
  *(uint4*)&Wtf[(size_t)gid * 8] = make_uint4(p[0], p[1], p[2], p[3]);
}

// ---------------- k3: fused scores (pipelined) ------------------------------
// Block: 64 rows x full U=512. 8 waves; wave w owns n-tiles w*4..w*4+3.
// A staged per 128-k chunk as bf16, double-buffered (2x16KB), XOR-swizzled.
// B fragments: contiguous 1KB wave loads from fragment-ordered Wtf (L2-res).
__global__ __launch_bounds__(512, 4) void scores_k(
    const float* __restrict__ values, const unsigned short* __restrict__ Wtf,
    const float* __restrict__ Q, const float* __restrict__ V1,
    float* __restrict__ scores) {
  __shared__ __align__(16) unsigned short Ab[2][64 * 128];  // 2 x 16KB
  __shared__ float sAcc[64];

  const int t = threadIdx.x;
  const int lane = t & 63;
  const int w = t >> 6;        // wave 0..7
  const int quad = lane >> 4;  // 0..3
  const int l15 = lane & 15;
  const int m0 = blockIdx.x * 64;
  const int b = m0 >> 11;  // /2048

  if (t < 64) sAcc[t] = 0.0f;

  // Staging geometry: thread t owns row sm = t>>3, 16 floats at col sp*16
  // of the current 128-k chunk. Writes two 16B chunks (XOR-swizzled by m&7).
  const int sm = t >> 3;  // 0..63
  const int sp = t & 7;   // 0..7
  const int sk = sm & 7;  // write swizzle key
  const float* src = values + (size_t)(m0 + sm) * 512 + sp * 16;
  const int wo0 = sm * 128 + (((2 * sp) ^ sk) * 8);
  const int wo1 = sm * 128 + (((2 * sp + 1) ^ sk) * 8);

  // ---- prologue: stage chunk 0 into buf 0
  {
    const f32x4* s4 = (const f32x4*)src;
    const f32x4 r0 = s4[0], r1 = s4[1], r2 = s4[2], r3 = s4[3];
    const unsigned int p0 = (unsigned int)f2bf(r0[0]) | ((unsigned int)f2bf(r0[1]) << 16);
    const unsigned int p1 = (unsigned int)f2bf(r0[2]) | ((unsigned int)f2bf(r0[3]) << 16);
    const unsigned int p2 = (unsigned int)f2bf(r1[0]) | ((unsigned int)f2bf(r1[1]) << 16);
    const unsigned int p3 = (unsigned int)f2bf(r1[2]) | ((unsigned int)f2bf(r1[3]) << 16);
    const unsigned int p4 = (unsigned int)f2bf(r2[0]) | ((unsigned int)f2bf(r2[1]) << 16);
    const unsigned int p5 = (unsigned int)f2bf(r2[2]) | ((unsigned int)f2bf(r2[3]) << 16);
    const unsigned int p6 = (unsigned int)f2bf(r3[0]) | ((unsigned int)f2bf(r3[1]) << 16);
    const unsigned int p7 = (unsigned int)f2bf(r3[2]) | ((unsigned int)f2bf(r3[3]) << 16);
    *(uint4*)&Ab[0][wo0] = make_uint4(p0, p1, p2, p3);
    *(uint4*)&Ab[0][wo1] = make_uint4(p4, p5, p6, p7);
  }
  __syncthreads();

  f32x4 acc[4][4];
#pragma unroll
  for (int mt = 0; mt < 4; ++mt)
#pragma unroll
    for (int nt = 0; nt < 4; ++nt) acc[mt][nt] = (f32x4){0.f, 0.f, 0.f, 0.f};

  const unsigned short* Bg = Wtf + (size_t)lane * 8;  // + ((ntile*16+ks)*512)
  const int sw = l15 & 7;  // A swizzle key (m&7 == l15&7)

#pragma unroll
  for (int c = 0; c < 4; ++c) {  // 4 k-chunks of 128
    f32x4 r0, r1, r2, r3;
    if (c < 3) {
      // T14 issue-early: next chunk's HBM loads in flight under the MFMAs
      const f32x4* s4 = (const f32x4*)(src + (c + 1) * 128);
      r0 = s4[0];
      r1 = s4[1];
      r2 = s4[2];
      r3 = s4[3];
      asm volatile("" : "+v"(r0), "+v"(r1), "+v"(r2), "+v"(r3));
    }

    const unsigned short* Ac = &Ab[c & 1][0];
#pragma unroll
    for (int kl = 0; kl < 4; ++kl) {  // 4 k-steps of 32 within chunk
      const int ks = c * 4 + kl;
      bf16x8 bfr[4], af[4];
#pragma unroll
      for (int nt = 0; nt < 4; ++nt)
        bfr[nt] = *(const bf16x8*)(Bg + (size_t)((w * 4 + nt) * 16 + ks) * 512);
#pragma unroll
      for (int mt = 0; mt < 4; ++mt)
        af[mt] = *(const bf16x8*)&Ac[(mt * 16 + l15) * 128 + (((kl * 4 + quad) ^ sw) * 8)];
#pragma unroll
      for (int mt = 0; mt < 4; ++mt)
#pragma unroll
        for (int nt = 0; nt < 4; ++nt)
          acc[mt][nt] = __builtin_amdgcn_mfma_f32_16x16x32_bf16(af[mt], bfr[nt],
                                                                acc[mt][nt], 0, 0, 0);
    }

    if (c < 3) {
      // write-late: convert + ds_write into the other buffer
      const unsigned int p0 = (unsigned int)f2bf(r0[0]) | ((unsigned int)f2bf(r0[1]) << 16);
      const unsigned int p1 = (unsigned int)f2bf(r0[2]) | ((unsigned int)f2bf(r0[3]) << 16);
      const unsigned int p2 = (unsigned int)f2bf(r1[0]) | ((unsigned int)f2bf(r1[1]) << 16);
      const unsigned int p3 = (unsigned int)f2bf(r1[2]) | ((unsigned int)f2bf(r1[3]) << 16);
      const unsigned int p4 = (unsigned int)f2bf(r2[0]) | ((unsigned int)f2bf(r2[1]) << 16);
      const unsigned int p5 = (unsigned int)f2bf(r2[2]) | ((unsigned int)f2bf(r2[3]) << 16);
      const unsigned int p6 = (unsigned int)f2bf(r3[0]) | ((unsigned int)f2bf(r3[1]) << 16);
      const unsigned int p7 = (unsigned int)f2bf(r3[2]) | ((unsigned int)f2bf(r3[3]) << 16);
      *(uint4*)&Ab[(c + 1) & 1][wo0] = make_uint4(p0, p1, p2, p3);
      *(uint4*)&Ab[(c + 1) & 1][wo1] = make_uint4(p4, p5, p6, p7);
    }
    __syncthreads();
  }

  // ---- epilogue: part[m] += tanh(acc + Q[b,n]) * V1[n], reduce over n
  // C/D layout: col(n) = lane&15, row(m within tile) = quad*4 + r
  float part[4][4];
#pragma unroll
  for (int mt = 0; mt < 4; ++mt)
#pragma unroll
    for (int r = 0; r < 4; ++r) part[mt][r] = 0.f;

#pragma unroll
  for (int nt = 0; nt < 4; ++nt) {
    const int n = w * 64 + nt * 16 + l15;
    const float qv = Q[b * 512 + n];
    const float v1 = V1[n];
#pragma unroll
    for (int mt = 0; mt < 4; ++mt)
#pragma unroll
      for (int r = 0; r < 4; ++r) {
        const float x = acc[mt][nt][r] + qv;
        const float e = fast_exp2(x * 2.8853900817779268f);  // e^{2x}
        const float th = 1.0f - 2.0f * fast_rcp(e + 1.0f);   // tanh(x)
        part[mt][r] += th * v1;
      }
  }
#pragma unroll
  for (int mt = 0; mt < 4; ++mt)
#pragma unroll
    for (int r = 0; r < 4; ++r) {
      float v = part[mt][r];
      v += __shfl_xor(v, 1);
      v += __shfl_xor(v, 2);
      v += __shfl_xor(v, 4);
      v += __shfl_xor(v, 8);
      if (l15 == 0) atomicAdd(&sAcc[mt * 16 + quad * 4 + r], v);
    }
  __syncthreads();
  if (t < 64) scores[m0 + t] = sAcc[t];
}

// ---------------- k4: context with fused softmax ----------------------------
// grid 1024: (b, s-chunk of 128); 512 thr. Each block recomputes softmax stats
// over all 2048 raw scores of its b (8KB read, trivial), then accumulates its
// 128-s chunk into out via atomicAdd (out zeroed by wt_k).
__global__ __launch_bounds__(512) void ctx_k(const float* __restrict__ values,
                                             const float* __restrict__ scores,
                                             float* __restrict__ out) {
  __shared__ float red[16];
  __shared__ float wsc[128];
  const int bid = blockIdx.x;
  const int b = bid >> 4, sc = bid & 15;
  const int t = threadIdx.x;
  const float* sb = scores + (size_t)b * 2048;
  const float v0 = sb[t], v1 = sb[t + 512], v2 = sb[t + 1024], v3 = sb[t + 1536];
  float mx = fmaxf(fmaxf(v0, v1), fmaxf(v2, v3));
#pragma unroll
  for (int o = 1; o < 64; o <<= 1) mx = fmaxf(mx, __shfl_xor(mx, o));
  if ((t & 63) == 0) red[t >> 6] = mx;
  __syncthreads();
  mx = fmaxf(fmaxf(fmaxf(red[0], red[1]), fmaxf(red[2], red[3])),
             fmaxf(fmaxf(red[4], red[5]), fmaxf(red[6], red[7])));
  const float L2E = 1.4426950408889634f;
  float sum = fast_exp2((v0 - mx) * L2E) + fast_exp2((v1 - mx) * L2E) +
              fast_exp2((v2 - mx) * L2E) + fast_exp2((v3 - mx) * L2E);
#pragma unroll
  for (int o = 1; o < 64; o <<= 1) sum += __shfl_xor(sum, o);
  if ((t & 63) == 0) red[8 + (t >> 6)] = sum;
  __syncthreads();
  sum = (red[8] + red[9]) + (red[10] + red[11]) + (red[12] + red[13]) +
        (red[14] + red[15]);
  const float inv = 1.0f / sum;
  if (t < 128) wsc[t] = fast_exp2((sb[sc * 128 + t] - mx) * L2E) * inv;
  __syncthreads();
  const float* vb = values + ((size_t)b * 2048 + sc * 128) * 512;
  float acc = 0.f;
#pragma unroll 8
  for (int s = 0; s < 128; ++s) acc += wsc[s] * vb[(size_t)s * 512 + t];
  atomicAdd(&out[b * 512 + t], acc);
}

extern "C" void kernel_launch(void* const* d_in, const int* in_sizes, int n_in,
                              void* d_out, int out_size, void* d_ws, size_t ws_size,
                              hipStream_t stream) {
  const float* query = (const float*)d_in[0];   // (64, 512)
  const float* values = (const float*)d_in[1];  // (64, 2048, 512)
  const float* W1 = (const float*)d_in[2];      // (512, 512)
  const float* W2 = (const float*)d_in[3];      // (512, 512)
  const float* V1 = (const float*)d_in[4];      // (512, 1)
  float* out = (float*)d_out;                   // (64, 512)

  char* ws = (char*)d_ws;
  float* Qp = (float*)ws;                                // 131072 B
  unsigned short* Wtp = (unsigned short*)(ws + 131072);  // 524288 B
  float* Sp = (float*)(ws + 131072 + 524288);            // 524288 B

  qk<<<dim3(64, 2), 256, 0, stream>>>(query, W1, Qp);
  wt_k<<<128, 256, 0, stream>>>(W2, Wtp, out);
  scores_k<<<2048, 512, 0, stream>>>(values, Wtp, Qp, V1, Sp);
  ctx_k<<<1024, 512, 0, stream>>>(values, Sp, out);
}

// Round 2
// 477.259 us; speedup vs baseline: 1.0589x; 1.0589x over previous
//
#include <hip/hip_runtime.h>

// AdditiveAttention on MI355X (gfx950)
// B=64, S=2048, D=512, U=512. All inputs fp32; output fp32 (B,D).
//
// R5: flash-style split-softmax fusion. scores_k (R3 staging, proven) now also
// computes per-block softmax partials (m_i, d_i) and a partial context
// ctx_i[512] = sum_r exp(s_r - m_i) * values[r][:] over its 64 rows (global
// fp32 re-read, L2-hot). ctx_k (full 268MB values re-read) is DELETED and
// replaced by comb_k: a 4MB rescale-and-sum. scores buffer round-trip gone.

typedef __attribute__((ext_vector_type(8))) short bf16x8;
typedef __attribute__((ext_vector_type(4))) float f32x4;

#if __has_builtin(__builtin_amdgcn_exp2f)
__device__ __forceinline__ float fast_exp2(float x) { return __builtin_amdgcn_exp2f(x); }
#else
__device__ __forceinline__ float fast_exp2(float x) { return exp2f(x); }
#endif
#if __has_builtin(__builtin_amdgcn_rcpf)
__device__ __forceinline__ float fast_rcp(float x) { return __builtin_amdgcn_rcpf(x); }
#else
__device__ __forceinline__ float fast_rcp(float x) { return 1.0f / x; }
#endif

__device__ __forceinline__ unsigned short f2bf(float f) {
  unsigned int u = __float_as_uint(f);
  u += 0x7fffu + ((u >> 16) & 1u);
  return (unsigned short)(u >> 16);
}

// ---------------- k1: Q = query @ W1  (64x2 blocks x 256 thr) ---------------
__global__ void qk(const float* __restrict__ query, const float* __restrict__ W1,
                   float* __restrict__ Q) {
  __shared__ float qrow[512];
  const int b = blockIdx.x, half = blockIdx.y, t = threadIdx.x;
  qrow[t] = query[b * 512 + t];
  qrow[t + 256] = query[b * 512 + t + 256];
  __syncthreads();
  const int u = half * 256 + t;
  float acc = 0.f;
#pragma unroll 8
  for (int k = 0; k < 512; ++k) acc += qrow[k] * W1[(size_t)k * 512 + u];
  Q[b * 512 + u] = acc;
}

// ---------------- k2: Wtf = fragment-ordered bf16(W2^T) ---------------------
// Wtf[((ntile*16+ks)*64 + quad*16 + l15)*8 + j] = bf16(W2[ks*32+quad*8+j][ntile*16+l15])
__global__ void wt_k(const float* __restrict__ W2, unsigned short* __restrict__ Wtf) {
  const int gid = blockIdx.x * 256 + threadIdx.x;  // 0..32767
  const int lane = gid & 63;
  const int g = gid >> 6;  // ntile*16 + ks
  const int ks = g & 15, ntile = g >> 4;
  const int l15 = lane & 15, quad = lane >> 4;
  const int n = ntile * 16 + l15;
  const int k0 = ks * 32 + quad * 8;
  unsigned int p[4];
#pragma unroll
  for (int jj = 0; jj < 4; ++jj) {
    const float a = W2[(size_t)(k0 + 2 * jj) * 512 + n];
    const float b = W2[(size_t)(k0 + 2 * jj + 1) * 512 + n];
    p[jj] = (unsigned int)f2bf(a) | ((unsigned int)f2bf(b) << 16);
  }
  *(uint4*)&Wtf[(size_t)gid * 8] = make_uint4(p[0], p[1], p[2], p[3]);
}

// ---------------- k3: fused scores + split-softmax partial context ----------
// Block: 64 rows x full U=512, K=512. 8 waves; wave w owns n-tiles w*4..w*4+3.
// A (values rows) -> bf16 LDS full-K, xor-swizzled 16B chunks (64KB).
// B fragments: contiguous 1KB wave loads from fragment-ordered Wtf (L2-res).
// Epilogue: tanh+V1 reduce -> 64 row scores in sAcc -> local softmax
// (m_i, d_i, w[64]) -> partial ctx column per thread (global fp32 re-read).
__global__ __launch_bounds__(512, 4) void scorectx_k(
    const float* __restrict__ values, const unsigned short* __restrict__ Wtf,
    const float* __restrict__ Q, const float* __restrict__ V1,
    float* __restrict__ Pstat, float* __restrict__ Pctx) {
  __shared__ __align__(16) unsigned short Ab[64 * 512];  // [m][512k], swizzled
  __shared__ float sAcc[64];
  __shared__ float wLDS[64];

  const int t = threadIdx.x;
  const int lane = t & 63;
  const int w = t >> 6;        // wave 0..7
  const int quad = lane >> 4;  // 0..3
  const int l15 = lane & 15;
  const int blk = blockIdx.x;
  const int m0 = blk * 64;
  const int b = m0 >> 11;  // /2048

  if (t < 64) sAcc[t] = 0.0f;

  // ---- stage A: 64 rows x 512 k, fp32 -> bf16, swizzled 16B chunks
  const float* Ag = values + (size_t)m0 * 512;
#pragma unroll
  for (int i = 0; i < 8; ++i) {
    const int c = i * 512 + t;  // chunk id: 64 rows x 64 chunks
    const int m = c >> 6;
    const int kc = c & 63;
    const float4* src = (const float4*)(Ag + (size_t)m * 512 + kc * 8);
    const float4 x = src[0], y = src[1];
    const unsigned int p0 = (unsigned int)f2bf(x.x) | ((unsigned int)f2bf(x.y) << 16);
    const unsigned int p1 = (unsigned int)f2bf(x.z) | ((unsigned int)f2bf(x.w) << 16);
    const unsigned int p2 = (unsigned int)f2bf(y.x) | ((unsigned int)f2bf(y.y) << 16);
    const unsigned int p3 = (unsigned int)f2bf(y.z) | ((unsigned int)f2bf(y.w) << 16);
    *(uint4*)&Ab[m * 512 + ((kc ^ (m & 7)) * 8)] = make_uint4(p0, p1, p2, p3);
  }
  __syncthreads();

  f32x4 acc[4][4];
#pragma unroll
  for (int mt = 0; mt < 4; ++mt)
#pragma unroll
    for (int nt = 0; nt < 4; ++nt) acc[mt][nt] = (f32x4){0.f, 0.f, 0.f, 0.f};

  const unsigned short* Bg = Wtf + (size_t)lane * 8;  // + ((ntile*16+ks)*512)
  const int sw = l15 & 7;  // A swizzle key (m&7 == l15&7)

#pragma unroll
  for (int ks = 0; ks < 16; ++ks) {  // 16 k-steps of 32
    bf16x8 bfr[4], af[4];
#pragma unroll
    for (int nt = 0; nt < 4; ++nt)
      bfr[nt] = *(const bf16x8*)(Bg + (size_t)((w * 4 + nt) * 16 + ks) * 512);
#pragma unroll
    for (int mt = 0; mt < 4; ++mt) {
      const int m = mt * 16 + l15;
      af[mt] = *(const bf16x8*)&Ab[m * 512 + (((ks * 4 + quad) ^ sw) * 8)];
    }
#pragma unroll
    for (int mt = 0; mt < 4; ++mt)
#pragma unroll
      for (int nt = 0; nt < 4; ++nt)
        acc[mt][nt] = __builtin_amdgcn_mfma_f32_16x16x32_bf16(af[mt], bfr[nt],
                                                              acc[mt][nt], 0, 0, 0);
  }

  // ---- epilogue: part[m] += tanh(acc + Q[b,n]) * V1[n], reduce over n
  // C/D layout: col(n) = lane&15, row(m within tile) = quad*4 + r
  float part[4][4];
#pragma unroll
  for (int mt = 0; mt < 4; ++mt)
#pragma unroll
    for (int r = 0; r < 4; ++r) part[mt][r] = 0.f;

#pragma unroll
  for (int nt = 0; nt < 4; ++nt) {
    const int n = w * 64 + nt * 16 + l15;
    const float qv = Q[b * 512 + n];
    const float v1 = V1[n];
#pragma unroll
    for (int mt = 0; mt < 4; ++mt)
#pragma unroll
      for (int r = 0; r < 4; ++r) {
        const float x = acc[mt][nt][r] + qv;
        const float e = fast_exp2(x * 2.8853900817779268f);  // e^{2x}
        const float th = 1.0f - 2.0f * fast_rcp(e + 1.0f);   // tanh(x)
        part[mt][r] += th * v1;
      }
  }
#pragma unroll
  for (int mt = 0; mt < 4; ++mt)
#pragma unroll
    for (int r = 0; r < 4; ++r) {
      float v = part[mt][r];
      v += __shfl_xor(v, 1);
      v += __shfl_xor(v, 2);
      v += __shfl_xor(v, 4);
      v += __shfl_xor(v, 8);
      if (l15 == 0) atomicAdd(&sAcc[mt * 16 + quad * 4 + r], v);
    }
  __syncthreads();

  // ---- local softmax partials (wave 0: lanes 0..63 own the 64 rows)
  const float L2E = 1.4426950408889634f;
  if (t < 64) {
    const float v = sAcc[t];
    float m = v;
#pragma unroll
    for (int o = 1; o < 64; o <<= 1) m = fmaxf(m, __shfl_xor(m, o));
    const float wv = fast_exp2((v - m) * L2E);
    float dsum = wv;
#pragma unroll
    for (int o = 1; o < 64; o <<= 1) dsum += __shfl_xor(dsum, o);
    wLDS[t] = wv;
    if (t == 0) {
      Pstat[2 * blk] = m;
      Pstat[2 * blk + 1] = dsum;
    }
  }
  __syncthreads();

  // ---- partial context: thread t owns column u=t over the block's 64 rows.
  // fp32 re-read from global (rows just streamed -> mostly L2-hit).
  const float* vrow = values + (size_t)m0 * 512 + t;
  float cacc = 0.f;
#pragma unroll 8
  for (int r = 0; r < 64; ++r) cacc += wLDS[r] * vrow[(size_t)r * 512];
  Pctx[(size_t)blk * 512 + t] = cacc;
}

// ---------------- k4: combine partials ------------------------------------
// grid 64 (one per b) x 512 thr. 32 partials per b: global max M, denom
// D = sum d_i*exp(m_i-M); out[b,d] = sum_i ctx_i[d]*exp(m_i-M) / D. 4MB read.
__global__ __launch_bounds__(512) void comb_k(const float* __restrict__ Pstat,
                                              const float* __restrict__ Pctx,
                                              float* __restrict__ out) {
  __shared__ float aL[32];
  __shared__ float Dsh;
  const int b = blockIdx.x, t = threadIdx.x;
  const float L2E = 1.4426950408889634f;
  if (t < 32) {
    const float2 st = ((const float2*)Pstat)[b * 32 + t];
    float m = st.x;
#pragma unroll
    for (int o = 1; o < 32; o <<= 1) m = fmaxf(m, __shfl_xor(m, o));
    const float a = fast_exp2((st.x - m) * L2E);
    float D = a * st.y;
#pragma unroll
    for (int o = 1; o < 32; o <<= 1) D += __shfl_xor(D, o);
    aL[t] = a;
    if (t == 0) Dsh = D;
  }
  __syncthreads();
  const float* pc = Pctx + (size_t)b * 32 * 512 + t;
  float acc = 0.f;
#pragma unroll
  for (int i = 0; i < 32; ++i) acc += aL[i] * pc[(size_t)i * 512];
  out[b * 512 + t] = acc / Dsh;
}

extern "C" void kernel_launch(void* const* d_in, const int* in_sizes, int n_in,
                              void* d_out, int out_size, void* d_ws, size_t ws_size,
                              hipStream_t stream) {
  const float* query = (const float*)d_in[0];   // (64, 512)
  const float* values = (const float*)d_in[1];  // (64, 2048, 512)
  const float* W1 = (const float*)d_in[2];      // (512, 512)
  const float* W2 = (const float*)d_in[3];      // (512, 512)
  const float* V1 = (const float*)d_in[4];      // (512, 1)
  float* out = (float*)d_out;                   // (64, 512)

  char* ws = (char*)d_ws;
  float* Qp = (float*)ws;                                // 131072 B
  unsigned short* Wtp = (unsigned short*)(ws + 131072);  // 524288 B
  float* Pstat = (float*)(ws + 131072 + 524288);         // 16384 B (2048 x 2)
  float* Pctx = (float*)(ws + 131072 + 524288 + 16384);  // 4 MB (2048 x 512)

  qk<<<dim3(64, 2), 256, 0, stream>>>(query, W1, Qp);
  wt_k<<<128, 256, 0, stream>>>(W2, Wtp);
  scorectx_k<<<2048, 512, 0, stream>>>(values, Wtp, Qp, V1, Pstat, Pctx);
  comb_k<<<64, 512, 0, stream>>>(Pstat, Pctx, out);
}